// Round 1
// baseline (179.034 us; speedup 1.0000x reference)
//
#include <hip/hip_runtime.h>
#include <hip/hip_bf16.h>

#define CIN 128
#define COUT 128

typedef __attribute__((ext_vector_type(8))) short short8;
typedef __attribute__((ext_vector_type(4))) float f32x4;

struct XPtrs { const float* p[17]; };

__device__ __forceinline__ unsigned short f2bf(float f) {
  unsigned u = __float_as_uint(f);
  // round-to-nearest-even bf16
  return (unsigned short)((u + 0x7fffu + ((u >> 16) & 1u)) >> 16);
}

__global__ __launch_bounds__(256) void diag_linear_kernel(
    XPtrs xp, const float* __restrict__ W, const float* __restrict__ bias,
    float* __restrict__ out) {
  const int p = blockIdx.y;            // board position 0..80
  const int r = p / 9, c = p % 9;
  const int diag = r + c;              // 0..16
  const int start = (diag > 8) ? (diag - 8) : 0;
  const int l = r - start;             // index within the diagonal
  const int L = 9 - ((diag > 8) ? (diag - 8) : (8 - diag));  // LENS[diag]
  const float* __restrict__ x = xp.p[diag];

  const int btile = blockIdx.x;        // 0..63 (128 batch rows each)
  const int t = threadIdx.x;
  const int lane = t & 63;
  const int wave = t >> 6;             // 0..3, each wave owns 32 batch rows
  const int lr = lane & 15;            // fragment row/col index
  const int lg = lane >> 4;            // fragment k-group

  // W staged as bf16, fragment-packed: [k_step s][k_group g][n][8 shorts]
  __shared__ short wlds[4][4][128][8];   // 32 KiB

  // ---- stage W[diag] -> LDS (bf16) ----
  {
    const int n = t & 127;
    const int kh = t >> 7;             // 0/1 : which 64-wide k-half
    const float* wrow = W + (size_t)diag * (COUT * CIN) + (size_t)n * CIN + kh * 64;
#pragma unroll
    for (int it = 0; it < 16; ++it) {
      const int k = kh * 64 + it * 4;
      float4 w4 = *(const float4*)(wrow + it * 4);
      const int s = k >> 5;
      const int g = (k >> 3) & 3;
      const int j0 = k & 7;            // 0 or 4
      unsigned u0 = (unsigned)f2bf(w4.x) | ((unsigned)f2bf(w4.y) << 16);
      unsigned u1 = (unsigned)f2bf(w4.z) | ((unsigned)f2bf(w4.w) << 16);
      *(uint2*)&wlds[s][g][n][j0] = make_uint2(u0, u1);
    }
  }

  // ---- load A fragments (X rows) global -> reg, convert to bf16 ----
  short8 afrag[2][4];
#pragma unroll
  for (int mb = 0; mb < 2; ++mb) {
    const int brow = btile * 128 + wave * 32 + mb * 16 + lr;
    const float* xr = x + ((size_t)brow * L + l) * CIN;
#pragma unroll
    for (int s = 0; s < 4; ++s) {
      float4 a0 = *(const float4*)(xr + s * 32 + lg * 8);
      float4 a1 = *(const float4*)(xr + s * 32 + lg * 8 + 4);
      short8 f;
      f[0] = (short)f2bf(a0.x); f[1] = (short)f2bf(a0.y);
      f[2] = (short)f2bf(a0.z); f[3] = (short)f2bf(a0.w);
      f[4] = (short)f2bf(a1.x); f[5] = (short)f2bf(a1.y);
      f[6] = (short)f2bf(a1.z); f[7] = (short)f2bf(a1.w);
      afrag[mb][s] = f;
    }
  }

  // bias fragment: one float per n-block
  float bfr[8];
#pragma unroll
  for (int nb = 0; nb < 8; ++nb)
    bfr[nb] = bias[diag * COUT + nb * 16 + lr];

  f32x4 acc[2][8];
#pragma unroll
  for (int mb = 0; mb < 2; ++mb)
#pragma unroll
    for (int nb = 0; nb < 8; ++nb)
      acc[mb][nb] = (f32x4){0.f, 0.f, 0.f, 0.f};

  __syncthreads();

  // ---- MFMA: acc[mb][nb] += A[mb] * B[nb] over 4 k-steps ----
#pragma unroll
  for (int nb = 0; nb < 8; ++nb) {
#pragma unroll
    for (int s = 0; s < 4; ++s) {
      short8 bfrag = *(const short8*)&wlds[s][lg][nb * 16 + lr][0];
      acc[0][nb] = __builtin_amdgcn_mfma_f32_16x16x32_bf16(afrag[0][s], bfrag, acc[0][nb], 0, 0, 0);
      acc[1][nb] = __builtin_amdgcn_mfma_f32_16x16x32_bf16(afrag[1][s], bfrag, acc[1][nb], 0, 0, 0);
    }
  }

  // ---- epilogue: bias add + store (C/D layout: row=(lg)*4+v, col=lr) ----
#pragma unroll
  for (int mb = 0; mb < 2; ++mb) {
#pragma unroll
    for (int v = 0; v < 4; ++v) {
      const size_t b = (size_t)btile * 128 + wave * 32 + mb * 16 + lg * 4 + v;
      float* orow = out + (b * 81 + p) * 128;
#pragma unroll
      for (int nb = 0; nb < 8; ++nb)
        orow[nb * 16 + lr] = acc[mb][nb][v] + bfr[nb];
    }
  }
}

extern "C" void kernel_launch(void* const* d_in, const int* in_sizes, int n_in,
                              void* d_out, int out_size, void* d_ws, size_t ws_size,
                              hipStream_t stream) {
  const float* W = (const float*)d_in[0];
  const float* bias = (const float*)d_in[1];
  XPtrs xp;
  for (int i = 0; i < 17; ++i) xp.p[i] = (const float*)d_in[2 + i];
  float* out = (float*)d_out;
  dim3 grid(64, 81);
  diag_linear_kernel<<<grid, dim3(256), 0, stream>>>(xp, W, bias, out);
}